// Round 5
// baseline (76.329 us; speedup 1.0000x reference)
//
#include <hip/hip_runtime.h>

#define NB 32
#define NH 32
#define NHKV 8
#define NG 4
#define ND 128
#define NP 16
#define NM 128
#define CH 128        // tokens per chunk
#define MAXC 12       // L <= 1500 <= 12*128
#define NITEMS (NB * NHKV * MAXC)   // 3072 work items
#define NBLOCKS 1024  // 4 blocks/CU * 256 CU, all co-resident

// ws_o : float[256][MAXC][NG][ND] unnormalized partial O  (~6.3 MB)
// ws_l : float[256][MAXC][NG]     partial sum of exp      (~49 KB)
// ws_cnt: int                     work-queue counter

__global__ __launch_bounds__(256, 4)
void pa_chunk(const float* __restrict__ q,
              const float* __restrict__ knew,
              const float* __restrict__ vnew,
              const float* __restrict__ kc,
              const float* __restrict__ vc,
              const int* __restrict__ bh_seq_lens,
              const int* __restrict__ page_table,
              const int* __restrict__ batch_mapping,
              float* __restrict__ ws_o,
              float* __restrict__ ws_l,
              int* __restrict__ ws_cnt)
{
    __shared__ int s_item;
    __shared__ int s_pages[CH / NP];                     // 8 pages
    __shared__ __align__(16) float4 s_part[4][32][NG];   // 8 KB
    __shared__ float s_sums[4][NG];

    const int tid = threadIdx.x;
    const int lane32 = tid & 31;
    const int tgrp = tid >> 5;                 // 0..7
    const bool selb0 = (lane32 & 1) != 0;
    const bool selb1 = (lane32 & 2) != 0;
    const float scale = 0.08838834764831845f;

    const float4* kc4 = reinterpret_cast<const float4*>(kc);
    const float4* vc4 = reinterpret_cast<const float4*>(vc);

    while (true) {
        if (tid == 0) s_item = atomicAdd(ws_cnt, 1);
        __syncthreads();
        const int item = s_item;
        __syncthreads();                       // next-iter write can't race this read
        if (item >= NITEMS) break;             // uniform exit

        const int bh = item / MAXC;
        const int c  = item - bh * MAXC;
        const int b = bh >> 3;
        const int h = bh & 7;
        const int slot = batch_mapping[b];
        const int seq = bh_seq_lens[slot * NHKV + h];
        const int L = seq + 1;
        const int t0 = c * CH;
        if (t0 >= L) continue;                 // inactive chunk (uniform)
        const int n = min(CH, L - t0);
        const int* pt = page_table + (slot * NHKV + h) * NM;

        if (tid < CH / NP) s_pages[tid] = pt[(t0 >> 4) + tid];

        const float4 q0 = *reinterpret_cast<const float4*>(q + (size_t)(b * NH + h * NG + 0) * ND + lane32 * 4);
        const float4 q1 = *reinterpret_cast<const float4*>(q + (size_t)(b * NH + h * NG + 1) * ND + lane32 * 4);
        const float4 q2 = *reinterpret_cast<const float4*>(q + (size_t)(b * NH + h * NG + 2) * ND + lane32 * 4);
        const float4 q3 = *reinterpret_cast<const float4*>(q + (size_t)(b * NH + h * NG + 3) * ND + lane32 * 4);

        const float4* knew4 = reinterpret_cast<const float4*>(knew + (size_t)(b * NHKV + h) * ND);
        const float4* vnew4 = reinterpret_cast<const float4*>(vnew + (size_t)(b * NHKV + h) * ND);

        __syncthreads();                       // s_pages ready

        float4 o0 = {0,0,0,0}, o1 = {0,0,0,0}, o2 = {0,0,0,0}, o3 = {0,0,0,0};
        float psum = 0.f;

        auto proc = [&](const float4 kv, const float4 vv) {
            float a0 = q0.x * kv.x + q0.y * kv.y + q0.z * kv.z + q0.w * kv.w;
            float a1 = q1.x * kv.x + q1.y * kv.y + q1.z * kv.z + q1.w * kv.w;
            float a2 = q2.x * kv.x + q2.y * kv.y + q2.z * kv.z + q2.w * kv.w;
            float a3 = q3.x * kv.x + q3.y * kv.y + q3.z * kv.z + q3.w * kv.w;
            a0 += __shfl_xor(a0, 1, 32); a1 += __shfl_xor(a1, 1, 32);
            a2 += __shfl_xor(a2, 1, 32); a3 += __shfl_xor(a3, 1, 32);
            a0 += __shfl_xor(a0, 2, 32); a1 += __shfl_xor(a1, 2, 32);
            a2 += __shfl_xor(a2, 2, 32); a3 += __shfl_xor(a3, 2, 32);
            float v = selb1 ? (selb0 ? a3 : a2) : (selb0 ? a1 : a0);
            v += __shfl_xor(v, 4, 32);
            v += __shfl_xor(v, 8, 32);
            v += __shfl_xor(v, 16, 32);
            const float pe = __expf(v * scale);   // |s| small: no max subtraction needed in fp32
            psum += pe;
            const float p0 = __shfl(pe, 0, 32);
            const float p1 = __shfl(pe, 1, 32);
            const float p2 = __shfl(pe, 2, 32);
            const float p3 = __shfl(pe, 3, 32);
            o0.x += p0 * vv.x; o0.y += p0 * vv.y; o0.z += p0 * vv.z; o0.w += p0 * vv.w;
            o1.x += p1 * vv.x; o1.y += p1 * vv.y; o1.z += p1 * vv.z; o1.w += p1 * vv.w;
            o2.x += p2 * vv.x; o2.y += p2 * vv.y; o2.z += p2 * vv.z; o2.w += p2 * vv.w;
            o3.x += p3 * vv.x; o3.y += p3 * vv.y; o3.z += p3 * vv.z; o3.w += p3 * vv.w;
        };

        const bool last = (t0 + CH >= L);

        if (!last) {
            #pragma unroll 2
            for (int i = 0; i < CH / (2 * NP); ++i) {
                const int pg0 = s_pages[2 * i];
                const int pg1 = s_pages[2 * i + 1];
                const float4 k0 = kc4[((size_t)pg0 * NP + tgrp    ) * 32 + lane32];
                const float4 k1 = kc4[((size_t)pg0 * NP + tgrp + 8) * 32 + lane32];
                const float4 k2 = kc4[((size_t)pg1 * NP + tgrp    ) * 32 + lane32];
                const float4 k3 = kc4[((size_t)pg1 * NP + tgrp + 8) * 32 + lane32];
                const float4 v0 = vc4[((size_t)pg0 * NP + tgrp    ) * 32 + lane32];
                const float4 v1 = vc4[((size_t)pg0 * NP + tgrp + 8) * 32 + lane32];
                const float4 v2 = vc4[((size_t)pg1 * NP + tgrp    ) * 32 + lane32];
                const float4 v3 = vc4[((size_t)pg1 * NP + tgrp + 8) * 32 + lane32];
                proc(k0, v0);
                proc(k1, v1);
                proc(k2, v2);
                proc(k3, v3);
            }
        } else {
            const int nf = (n - 1) & ~(NP - 1);
            for (int p = 0; p < (nf >> 4); ++p) {
                const int pg = s_pages[p];
                const float4 k0 = kc4[((size_t)pg * NP + tgrp    ) * 32 + lane32];
                const float4 k1 = kc4[((size_t)pg * NP + tgrp + 8) * 32 + lane32];
                const float4 v0 = vc4[((size_t)pg * NP + tgrp    ) * 32 + lane32];
                const float4 v1 = vc4[((size_t)pg * NP + tgrp + 8) * 32 + lane32];
                proc(k0, v0);
                proc(k1, v1);
            }
            for (int t = nf + tgrp; t < n; t += 8) {
                const int gt = t0 + t;
                float4 kv, vv;
                if (gt == seq) {
                    kv = knew4[lane32];
                    vv = vnew4[lane32];
                } else {
                    const int pg = s_pages[t >> 4];
                    kv = kc4[((size_t)pg * NP + (t & 15)) * 32 + lane32];
                    vv = vc4[((size_t)pg * NP + (t & 15)) * 32 + lane32];
                }
                proc(kv, vv);
            }
        }

        // pair the two tgroups of each wave
        o0.x += __shfl_xor(o0.x, 32, 64); o0.y += __shfl_xor(o0.y, 32, 64);
        o0.z += __shfl_xor(o0.z, 32, 64); o0.w += __shfl_xor(o0.w, 32, 64);
        o1.x += __shfl_xor(o1.x, 32, 64); o1.y += __shfl_xor(o1.y, 32, 64);
        o1.z += __shfl_xor(o1.z, 32, 64); o1.w += __shfl_xor(o1.w, 32, 64);
        o2.x += __shfl_xor(o2.x, 32, 64); o2.y += __shfl_xor(o2.y, 32, 64);
        o2.z += __shfl_xor(o2.z, 32, 64); o2.w += __shfl_xor(o2.w, 32, 64);
        o3.x += __shfl_xor(o3.x, 32, 64); o3.y += __shfl_xor(o3.y, 32, 64);
        o3.z += __shfl_xor(o3.z, 32, 64); o3.w += __shfl_xor(o3.w, 32, 64);
        psum += __shfl_xor(psum, 32, 64);

        if ((tid & 32) == 0) {
            const int pr = tgrp >> 1;
            s_part[pr][lane32][0] = o0;
            s_part[pr][lane32][1] = o1;
            s_part[pr][lane32][2] = o2;
            s_part[pr][lane32][3] = o3;
            if (lane32 < NG) s_sums[pr][lane32] = psum;
        }
        __syncthreads();

        if (tid < 128) {
            const int g  = tid >> 5;
            const int sl = tid & 31;
            float4 acc = {0,0,0,0};
            #pragma unroll
            for (int pr = 0; pr < 4; ++pr) {
                const float4 t4 = s_part[pr][sl][g];
                acc.x += t4.x; acc.y += t4.y; acc.z += t4.z; acc.w += t4.w;
            }
            float* op = ws_o + ((size_t)(bh * MAXC + c) * NG + g) * ND + sl * 4;
            *reinterpret_cast<float4*>(op) = acc;
        }
        if (tid < NG) {
            ws_l[(size_t)(bh * MAXC + c) * NG + tid] =
                s_sums[0][tid] + s_sums[1][tid] + s_sums[2][tid] + s_sums[3][tid];
        }
        // s_part/s_pages reuse is guarded by the two s_item barriers at loop top
    }
}

__global__ __launch_bounds__(512, 2)
void pa_combine(const float* __restrict__ ws_o,
                const float* __restrict__ ws_l,
                const int* __restrict__ bh_seq_lens,
                const int* __restrict__ batch_mapping,
                float* __restrict__ out)
{
    const int bh = blockIdx.x;
    const int b = bh >> 3;
    const int h = bh & 7;
    const int L = bh_seq_lens[batch_mapping[b] * NHKV + h] + 1;
    const int nc = (L + CH - 1) / CH;

    const int tid = threadIdx.x;
    const int g = tid >> 7;
    const int d = tid & 127;

    float num = 0.f, den = 0.f;
    #pragma unroll
    for (int c = 0; c < MAXC; ++c) {
        if (c < nc) {
            num += ws_o[((size_t)(bh * MAXC + c) * NG + g) * ND + d];
            den += ws_l[(size_t)(bh * MAXC + c) * NG + g];
        }
    }
    out[(size_t)(b * NH + h * NG + g) * ND + d] = num / den;
}

extern "C" void kernel_launch(void* const* d_in, const int* in_sizes, int n_in,
                              void* d_out, int out_size, void* d_ws, size_t ws_size,
                              hipStream_t stream) {
    const float* q    = (const float*)d_in[0];
    const float* knew = (const float*)d_in[1];
    const float* vnew = (const float*)d_in[2];
    const float* kc   = (const float*)d_in[3];
    const float* vc   = (const float*)d_in[4];
    const int* seqls  = (const int*)d_in[5];
    const int* ptab   = (const int*)d_in[6];
    const int* bmap   = (const int*)d_in[7];
    float* out        = (float*)d_out;

    float* ws_o  = (float*)d_ws;
    float* ws_l  = ws_o + (size_t)NB * NHKV * MAXC * NG * ND;
    int*   ws_cnt = (int*)(ws_l + (size_t)NB * NHKV * MAXC * NG);

    hipMemsetAsync(ws_cnt, 0, sizeof(int), stream);   // graph-capturable memset node
    pa_chunk<<<NBLOCKS, 256, 0, stream>>>(q, knew, vnew, kc, vc, seqls, ptab, bmap, ws_o, ws_l, ws_cnt);
    pa_combine<<<NB * NHKV, 512, 0, stream>>>(ws_o, ws_l, seqls, bmap, out);
}

// Round 6
// 53.127 us; speedup vs baseline: 1.4367x; 1.4367x over previous
//
#include <hip/hip_runtime.h>

#define NB 32
#define NH 32
#define NHKV 8
#define NG 4
#define ND 128
#define NP 16
#define NM 128
#define CH 128        // tokens per chunk
#define MAXC 12       // L <= 1500 <= 12*128

// ws_o : float[256][MAXC][NG][ND] unnormalized partial O  (~6.3 MB)
// ws_l : float[256][MAXC][NG]     partial sum of exp      (~49 KB)

__global__ __launch_bounds__(256, 8)   // force vgpr<=64 -> 8 blocks/CU, all active blocks co-resident
void pa_chunk(const float* __restrict__ q,
              const float* __restrict__ knew,
              const float* __restrict__ vnew,
              const float* __restrict__ kc,
              const float* __restrict__ vc,
              const int* __restrict__ bh_seq_lens,
              const int* __restrict__ page_table,
              const int* __restrict__ batch_mapping,
              float* __restrict__ ws_o,
              float* __restrict__ ws_l)
{
    __shared__ int s_pages[CH / NP];                     // 8 pages
    __shared__ __align__(16) float4 s_part[4][32][NG];   // 8 KB
    __shared__ float s_sums[4][NG];

    const int bh = blockIdx.x;
    const int c  = blockIdx.y;
    const int b = bh >> 3;
    const int h = bh & 7;
    const int slot = batch_mapping[b];
    const int seq = bh_seq_lens[slot * NHKV + h];
    const int L = seq + 1;
    const int t0 = c * CH;
    if (t0 >= L) return;
    const int n = min(CH, L - t0);
    const int* pt = page_table + (slot * NHKV + h) * NM;

    const int tid = threadIdx.x;
    const int lane32 = tid & 31;
    const int tgrp = tid >> 5;                 // 0..7

    if (tid < CH / NP) s_pages[tid] = pt[(t0 >> 4) + tid];

    const float4 q0 = *reinterpret_cast<const float4*>(q + (size_t)(b * NH + h * NG + 0) * ND + lane32 * 4);
    const float4 q1 = *reinterpret_cast<const float4*>(q + (size_t)(b * NH + h * NG + 1) * ND + lane32 * 4);
    const float4 q2 = *reinterpret_cast<const float4*>(q + (size_t)(b * NH + h * NG + 2) * ND + lane32 * 4);
    const float4 q3 = *reinterpret_cast<const float4*>(q + (size_t)(b * NH + h * NG + 3) * ND + lane32 * 4);

    const float4* kc4 = reinterpret_cast<const float4*>(kc);
    const float4* vc4 = reinterpret_cast<const float4*>(vc);
    const float scale = 0.08838834764831845f;
    const bool selb0 = (lane32 & 1) != 0;
    const bool selb1 = (lane32 & 2) != 0;

    __syncthreads();   // s_pages ready

    float4 o0 = {0,0,0,0}, o1 = {0,0,0,0}, o2 = {0,0,0,0}, o3 = {0,0,0,0};
    float psum = 0.f;

    auto proc = [&](const float4 kv, const float4 vv) {
        float a0 = q0.x * kv.x + q0.y * kv.y + q0.z * kv.z + q0.w * kv.w;
        float a1 = q1.x * kv.x + q1.y * kv.y + q1.z * kv.z + q1.w * kv.w;
        float a2 = q2.x * kv.x + q2.y * kv.y + q2.z * kv.z + q2.w * kv.w;
        float a3 = q3.x * kv.x + q3.y * kv.y + q3.z * kv.z + q3.w * kv.w;
        a0 += __shfl_xor(a0, 1, 32); a1 += __shfl_xor(a1, 1, 32);
        a2 += __shfl_xor(a2, 1, 32); a3 += __shfl_xor(a3, 1, 32);
        a0 += __shfl_xor(a0, 2, 32); a1 += __shfl_xor(a1, 2, 32);
        a2 += __shfl_xor(a2, 2, 32); a3 += __shfl_xor(a3, 2, 32);
        float v = selb1 ? (selb0 ? a3 : a2) : (selb0 ? a1 : a0);
        v += __shfl_xor(v, 4, 32);
        v += __shfl_xor(v, 8, 32);
        v += __shfl_xor(v, 16, 32);
        const float pe = __expf(v * scale);   // |s| small: fp32-safe without max subtraction
        psum += pe;
        const float p0 = __shfl(pe, 0, 32);
        const float p1 = __shfl(pe, 1, 32);
        const float p2 = __shfl(pe, 2, 32);
        const float p3 = __shfl(pe, 3, 32);
        o0.x += p0 * vv.x; o0.y += p0 * vv.y; o0.z += p0 * vv.z; o0.w += p0 * vv.w;
        o1.x += p1 * vv.x; o1.y += p1 * vv.y; o1.z += p1 * vv.z; o1.w += p1 * vv.w;
        o2.x += p2 * vv.x; o2.y += p2 * vv.y; o2.z += p2 * vv.z; o2.w += p2 * vv.w;
        o3.x += p3 * vv.x; o3.y += p3 * vv.y; o3.z += p3 * vv.z; o3.w += p3 * vv.w;
    };

    const bool last = (t0 + CH >= L);

    if (!last) {
        // one page (16 tokens) per macro-iter: 4 float4 loads in flight, low VGPR
        #pragma unroll 1
        for (int p = 0; p < CH / NP; ++p) {
            const int pg = s_pages[p];
            const size_t base = (size_t)pg * NP * 32 + lane32;
            const float4 k0 = kc4[base + (size_t)tgrp * 32];
            const float4 k1 = kc4[base + (size_t)(tgrp + 8) * 32];
            const float4 v0 = vc4[base + (size_t)tgrp * 32];
            const float4 v1 = vc4[base + (size_t)(tgrp + 8) * 32];
            proc(k0, v0);
            proc(k1, v1);
        }
    } else {
        const int nf = (n - 1) & ~(NP - 1);
        #pragma unroll 1
        for (int p = 0; p < (nf >> 4); ++p) {
            const int pg = s_pages[p];
            const size_t base = (size_t)pg * NP * 32 + lane32;
            const float4 k0 = kc4[base + (size_t)tgrp * 32];
            const float4 k1 = kc4[base + (size_t)(tgrp + 8) * 32];
            const float4 v0 = vc4[base + (size_t)tgrp * 32];
            const float4 v1 = vc4[base + (size_t)(tgrp + 8) * 32];
            proc(k0, v0);
            proc(k1, v1);
        }
        const float4* knew4 = reinterpret_cast<const float4*>(knew + (size_t)(b * NHKV + h) * ND);
        const float4* vnew4 = reinterpret_cast<const float4*>(vnew + (size_t)(b * NHKV + h) * ND);
        for (int t = nf + tgrp; t < n; t += 8) {
            const int gt = t0 + t;
            float4 kv, vv;
            if (gt == seq) {
                kv = knew4[lane32];
                vv = vnew4[lane32];
            } else {
                const int pg = s_pages[t >> 4];
                kv = kc4[((size_t)pg * NP + (t & 15)) * 32 + lane32];
                vv = vc4[((size_t)pg * NP + (t & 15)) * 32 + lane32];
            }
            proc(kv, vv);
        }
    }

    // pair the two tgroups of each wave
    o0.x += __shfl_xor(o0.x, 32, 64); o0.y += __shfl_xor(o0.y, 32, 64);
    o0.z += __shfl_xor(o0.z, 32, 64); o0.w += __shfl_xor(o0.w, 32, 64);
    o1.x += __shfl_xor(o1.x, 32, 64); o1.y += __shfl_xor(o1.y, 32, 64);
    o1.z += __shfl_xor(o1.z, 32, 64); o1.w += __shfl_xor(o1.w, 32, 64);
    o2.x += __shfl_xor(o2.x, 32, 64); o2.y += __shfl_xor(o2.y, 32, 64);
    o2.z += __shfl_xor(o2.z, 32, 64); o2.w += __shfl_xor(o2.w, 32, 64);
    o3.x += __shfl_xor(o3.x, 32, 64); o3.y += __shfl_xor(o3.y, 32, 64);
    o3.z += __shfl_xor(o3.z, 32, 64); o3.w += __shfl_xor(o3.w, 32, 64);
    psum += __shfl_xor(psum, 32, 64);

    if ((tid & 32) == 0) {
        const int pr = tgrp >> 1;              // wave index 0..3
        s_part[pr][lane32][0] = o0;
        s_part[pr][lane32][1] = o1;
        s_part[pr][lane32][2] = o2;
        s_part[pr][lane32][3] = o3;
        if (lane32 < NG) s_sums[pr][lane32] = psum;
    }
    __syncthreads();

    if (tid < 128) {
        const int g  = tid >> 5;
        const int sl = tid & 31;
        float4 acc = {0,0,0,0};
        #pragma unroll
        for (int pr = 0; pr < 4; ++pr) {
            const float4 t4 = s_part[pr][sl][g];
            acc.x += t4.x; acc.y += t4.y; acc.z += t4.z; acc.w += t4.w;
        }
        float* op = ws_o + ((size_t)(bh * MAXC + c) * NG + g) * ND + sl * 4;
        *reinterpret_cast<float4*>(op) = acc;
    }
    if (tid < NG) {
        ws_l[(size_t)(bh * MAXC + c) * NG + tid] =
            s_sums[0][tid] + s_sums[1][tid] + s_sums[2][tid] + s_sums[3][tid];
    }
}

__global__ __launch_bounds__(512, 2)
void pa_combine(const float* __restrict__ ws_o,
                const float* __restrict__ ws_l,
                const int* __restrict__ bh_seq_lens,
                const int* __restrict__ batch_mapping,
                float* __restrict__ out)
{
    const int bh = blockIdx.x;
    const int b = bh >> 3;
    const int h = bh & 7;
    const int L = bh_seq_lens[batch_mapping[b] * NHKV + h] + 1;
    const int nc = (L + CH - 1) / CH;

    const int tid = threadIdx.x;
    const int g = tid >> 7;
    const int d = tid & 127;

    float num = 0.f, den = 0.f;
    #pragma unroll
    for (int c = 0; c < MAXC; ++c) {
        if (c < nc) {
            num += ws_o[((size_t)(bh * MAXC + c) * NG + g) * ND + d];
            den += ws_l[(size_t)(bh * MAXC + c) * NG + g];
        }
    }
    out[(size_t)(b * NH + h * NG + g) * ND + d] = num / den;
}

extern "C" void kernel_launch(void* const* d_in, const int* in_sizes, int n_in,
                              void* d_out, int out_size, void* d_ws, size_t ws_size,
                              hipStream_t stream) {
    const float* q    = (const float*)d_in[0];
    const float* knew = (const float*)d_in[1];
    const float* vnew = (const float*)d_in[2];
    const float* kc   = (const float*)d_in[3];
    const float* vc   = (const float*)d_in[4];
    const int* seqls  = (const int*)d_in[5];
    const int* ptab   = (const int*)d_in[6];
    const int* bmap   = (const int*)d_in[7];
    float* out        = (float*)d_out;

    float* ws_o = (float*)d_ws;
    float* ws_l = ws_o + (size_t)NB * NHKV * MAXC * NG * ND;

    dim3 grid(NB * NHKV, MAXC);
    pa_chunk<<<grid, 256, 0, stream>>>(q, knew, vnew, kc, vc, seqls, ptab, bmap, ws_o, ws_l);
    pa_combine<<<NB * NHKV, 512, 0, stream>>>(ws_o, ws_l, seqls, bmap, out);
}